// Round 15
// baseline (200.946 us; speedup 1.0000x reference)
//
#include <hip/hip_runtime.h>

#define NB 4
#define NCH 256
#define NTOK 4096

typedef _Float16 f16x4 __attribute__((ext_vector_type(4)));
typedef _Float16 f16x8 __attribute__((ext_vector_type(8)));
typedef __fp16 h16x2 __attribute__((ext_vector_type(2)));
typedef float f32x4 __attribute__((ext_vector_type(4)));

union F2H  { h16x2 h; int i; };
union U64  { uint2 u; f16x4 h; int2 i2; };

// LDS-only barrier: do NOT drain vmcnt (stores stay in flight).
#define LDS_BARRIER() asm volatile("s_waitcnt lgkmcnt(0)\n\ts_barrier" ::: "memory")

// ---------------- K0: pack Wq/Wk/Wv -> fp16 [320][256] ----------------
__global__ __launch_bounds__(256) void wpack_kernel(
    const float* __restrict__ Wq, const float* __restrict__ Wk,
    const float* __restrict__ Wv, _Float16* __restrict__ W16)
{
    int g = blockIdx.x * 256 + threadIdx.x;
    if (g >= 320 * 64) return;
    int o = g >> 6, c4 = g & 63;
    const float* src = (o < 32) ? (Wq + o * NCH) :
                       (o < 64) ? (Wk + (o - 32) * NCH) : (Wv + (o - 64) * NCH);
    float4 v = ((const float4*)src)[c4];
    f16x4 p;
    p[0] = (_Float16)v.x; p[1] = (_Float16)v.y;
    p[2] = (_Float16)v.z; p[3] = (_Float16)v.w;
    *(f16x4*)(W16 + (size_t)o * NCH + c4 * 4) = p;
}

// ---------------- K1: QKV projection via MFMA ----------------
__global__ __launch_bounds__(256) void qkv_mfma_kernel(
    const float* __restrict__ x, const _Float16* __restrict__ W16,
    const float* __restrict__ bq, const float* __restrict__ bk,
    const float* __restrict__ bv,
    _Float16* __restrict__ qkT, _Float16* __restrict__ vbuf)
{
    __shared__ char xs[32 * 512];            // [n][c] f16, row 512B, swizzled
    __shared__ _Float16 vls[256 * 36];       // [o][n] f16, pitch 36 (72B, ~2-way banks)
    const int tid = threadIdx.x;
    const int b = blockIdx.x & 3;
    const int n0 = (blockIdx.x >> 2) << 5;
    const float* xb = x + (size_t)b * NCH * NTOK + n0;

    {   // stage: thread handles 4 consecutive c x 8 n; pack 4 c -> b64 per n
        const int c4 = tid & 63, no = tid >> 6;
        float vals[4][8];
        #pragma unroll
        for (int u = 0; u < 4; ++u) {
            const float* xr = xb + (size_t)(c4 * 4 + u) * NTOK + no * 8;
            float4 a = *(const float4*)xr;
            float4 b2 = *(const float4*)(xr + 4);
            vals[u][0]=a.x; vals[u][1]=a.y; vals[u][2]=a.z; vals[u][3]=a.w;
            vals[u][4]=b2.x; vals[u][5]=b2.y; vals[u][6]=b2.z; vals[u][7]=b2.w;
        }
        #pragma unroll
        for (int j = 0; j < 8; ++j) {
            const int n = no * 8 + j;
            f16x4 pk;
            pk[0]=(_Float16)vals[0][j]; pk[1]=(_Float16)vals[1][j];
            pk[2]=(_Float16)vals[2][j]; pk[3]=(_Float16)vals[3][j];
            *(f16x4*)(xs + n * 512 + ((c4 * 8) ^ ((n & 7) << 4))) = pk;
        }
    }
    __syncthreads();

    const int w = tid >> 6, l = tid & 63;
    const int iofs = l & 15, h = l >> 4;

    f32x4 acc[5][2];
    #pragma unroll
    for (int ot = 0; ot < 5; ++ot)
        #pragma unroll
        for (int nt = 0; nt < 2; ++nt) acc[ot][nt] = (f32x4){0.f,0.f,0.f,0.f};

    #pragma unroll
    for (int kk = 0; kk < 8; ++kk) {
        f16x8 bf[2];
        #pragma unroll
        for (int nt = 0; nt < 2; ++nt) {
            const int n = nt * 16 + iofs;
            bf[nt] = *(const f16x8*)(xs + n * 512 + ((kk * 64 + h * 16) ^ ((n & 7) << 4)));
        }
        #pragma unroll
        for (int ot = 0; ot < 5; ++ot) {
            const int og = w * 5 + ot;
            f16x8 af = *(const f16x8*)(W16 + (size_t)(og * 16 + iofs) * NCH + kk * 32 + h * 8);
            #pragma unroll
            for (int nt = 0; nt < 2; ++nt)
                acc[ot][nt] = __builtin_amdgcn_mfma_f32_16x16x32_f16(af, bf[nt], acc[ot][nt], 0, 0, 0);
        }
    }

    // epilogue: q/k direct; v -> LDS transpose tile
    #pragma unroll
    for (int ot = 0; ot < 5; ++ot) {
        const int og = w * 5 + ot;
        float4 bias;
        if (og < 2)      bias = *(const float4*)(bq + og * 16 + 4 * h);
        else if (og < 4) bias = *(const float4*)(bk + (og - 2) * 16 + 4 * h);
        else             bias = *(const float4*)(bv + (og - 4) * 16 + 4 * h);
        #pragma unroll
        for (int nt = 0; nt < 2; ++nt) {
            const int n = n0 + nt * 16 + iofs;
            f32x4 a = acc[ot][nt];
            if (og < 4) {
                f16x4 pk;
                pk[0] = (_Float16)(a[0] + bias.x); pk[1] = (_Float16)(a[1] + bias.y);
                pk[2] = (_Float16)(a[2] + bias.z); pk[3] = (_Float16)(a[3] + bias.w);
                const int col = (og < 2) ? (og * 16 + 4 * h) : (32 + (og - 2) * 16 + 4 * h);
                *(f16x4*)(qkT + (size_t)(b * NTOK + n) * 64 + col) = pk;
            } else {
                const int vr0 = (og - 4) * 16 + 4 * h;
                const int nl = nt * 16 + iofs;
                const float bb[4] = {bias.x, bias.y, bias.z, bias.w};
                #pragma unroll
                for (int r = 0; r < 4; ++r)
                    vls[(vr0 + r) * 36 + nl] = (_Float16)(a[r] + bb[r]);
            }
        }
    }
    __syncthreads();
    {   // v write-out: 4 lanes per o-row, 16B each -> 64B contiguous per row
        const int vr = tid >> 2;           // 0..63
        const int piece = tid & 3;
        #pragma unroll
        for (int pass = 0; pass < 4; ++pass) {
            const int row = pass * 64 + vr;
            f16x8 val = *(const f16x8*)(&vls[row * 36 + piece * 8]);
            *(f16x8*)(vbuf + (size_t)(b * NCH + row) * NTOK + n0 + piece * 8) = val;
        }
    }
}

// ---------------- K2: softmax row-sums (atomic partial sums) ----------------
// grid 2048: (b, 64-i block, 512-j eighth)
__global__ __launch_bounds__(256) void rowsum_kernel(
    const _Float16* __restrict__ qkT, float* __restrict__ rs_sum)
{
    const int bid = blockIdx.x;
    const int b = bid >> 9;
    const int rem = bid & 511;
    const int ib = rem >> 3, js = rem & 7;
    const int tid = threadIdx.x;
    const int w = tid >> 6, l = tid & 63;
    const int iofs = l & 15, h = l >> 4;
    const int i16 = ib * 64 + w * 16;
    const int j0 = js * 512;
    const _Float16* qk_b = qkT + (size_t)b * NTOK * 64;

    f16x8 qfrag = *(const f16x8*)(qk_b + (size_t)(i16 + iofs) * 64 + h * 8);
    float sums[4] = {0.f, 0.f, 0.f, 0.f};
    const f32x4 zero = {0.f, 0.f, 0.f, 0.f};
    #pragma unroll 4
    for (int jt = 0; jt < 32; ++jt) {
        f16x8 kfrag = *(const f16x8*)(qk_b + (size_t)(j0 + jt*16 + iofs) * 64 + 32 + h * 8);
        f32x4 s = __builtin_amdgcn_mfma_f32_16x16x32_f16(kfrag, qfrag, zero, 0, 0, 0);
        #pragma unroll
        for (int r = 0; r < 4; ++r) sums[r] += __expf(s[r]);
    }
    float tot = sums[0] + sums[1] + sums[2] + sums[3];
    tot += __shfl_xor(tot, 16, 64);
    tot += __shfl_xor(tot, 32, 64);
    if (l < 16) atomicAdd(&rs_sum[b * NTOK + i16 + iofs], tot);
}

// ---------------- K3: fused (R12 base), LOADS-BEFORE-STORES issue order ----------------
// Grid 512 = (4b x 128 i-tiles), 512 thr (8 waves), chunk = 256 j.
// Per chunk: phaseA(c+1) [kfrag loads + QK + LDS] -> phaseB(c) [vfrag loads + PV]
// -> sched_barrier -> phaseW(c) [atn nt stores LAST]. A chunk's stores are never
// older than any wait until the NEXT chunk's kfrag wait -> 1 full chunk of
// background commit slack; PV never gates on store commit (vmcnt FIFO order).
__global__ __launch_bounds__(512, 2) void attn_pv_kernel(
    const _Float16* __restrict__ qkT, const _Float16* __restrict__ vbuf,
    const float* __restrict__ rs_sum, const float* __restrict__ x,
    const float* __restrict__ gamma, float* __restrict__ out, float* __restrict__ atn)
{
    __shared__ char P[2][32 * 512];
    const int tid = threadIdx.x;
    const int w = tid >> 6, l = tid & 63;   // w: 0..7
    const int iofs = l & 15, h = l >> 4;
    const int xk = blockIdx.x & 7, rest = blockIdx.x >> 3;   // grid 512
    const int b = xk >> 1;
    const int itb = (rest << 1) | (xk & 1);   // 0..127
    const int i0 = itb << 5;                  // 32 i-rows per block

    const _Float16* qk_b = qkT + (size_t)b * NTOK * 64;
    const _Float16* v_b  = vbuf + (size_t)b * NCH * NTOK;
    float* atn_b = atn + (size_t)b * NTOK * NTOK;
    const int c0w = w * 32;                   // wave owns 32 c
    const float LOG2E = 1.44269504f;

    f16x8 qfrag[2];
    float rsl[2];
    #pragma unroll
    for (int ig = 0; ig < 2; ++ig) {
        qfrag[ig] = *(const f16x8*)(qk_b + (size_t)(i0 + ig*16 + iofs) * 64 + h * 8);
        rsl[ig] = -__log2f(rs_sum[b * NTOK + i0 + ig*16 + iofs]);
    }

    const f32x4 zero = {0.f, 0.f, 0.f, 0.f};
    f32x4 acc[2][2];
    #pragma unroll
    for (int ig = 0; ig < 2; ++ig)
        #pragma unroll
        for (int ct = 0; ct < 2; ++ct) acc[ig][ct] = zero;

    auto phaseA = [&](int chunk, int buf) {
        const int jbase = chunk * 256 + w * 32;
        #pragma unroll
        for (int jt = 0; jt < 2; ++jt) {
            const int jg = jbase + jt * 16;
            f16x8 kfrag = *(const f16x8*)(qk_b + (size_t)(jg + iofs) * 64 + 32 + h * 8);
            #pragma unroll
            for (int ig = 0; ig < 2; ++ig) {
                f32x4 s = __builtin_amdgcn_mfma_f32_16x16x32_f16(kfrag, qfrag[ig], zero, 0, 0, 0);
                f32x4 pv;
                #pragma unroll
                for (int r = 0; r < 4; ++r)
                    pv[r] = __builtin_amdgcn_exp2f(__builtin_fmaf(s[r], LOG2E, rsl[ig]));
                F2H p0, p1;
                p0.h = __builtin_amdgcn_cvt_pkrtz(pv[0], pv[1]);
                p1.h = __builtin_amdgcn_cvt_pkrtz(pv[2], pv[3]);
                const int iloc = ig * 16 + iofs;
                const int jloc = w * 32 + jt * 16 + 4 * h;
                const int byte = iloc * 512 + ((jloc * 2) ^ ((iloc & 7) << 4));
                U64 u; u.i2.x = p0.i; u.i2.y = p1.i;
                *(int2*)(P[buf] + byte) = u.i2;
            }
        }
    };

    // phaseW: LDS -> atn, full-128B-line nt stores. Issued LAST in each chunk.
    auto phaseW = [&](int chunk, int buf) {
        const int lg = tid & 7;
        const int g = tid >> 3;            // 0..63
        const int row = g & 31;
        const int seg = g >> 5;            // 0..1 (128-j segment)
        const int sw = (row & 7) << 4;
        float* arow = atn_b + (size_t)(i0 + row) * NTOK + chunk * 256 + seg * 128;
        #pragma unroll
        for (int u = 0; u < 4; ++u) {
            const int jf = u * 32 + lg * 4;           // within segment, f16 idx
            const int jbyte = seg * 256 + jf * 2;
            U64 v; v.i2 = *(const int2*)(P[buf] + row * 512 + (jbyte ^ sw));
            f32x4 st = {(float)v.h[0], (float)v.h[1], (float)v.h[2], (float)v.h[3]};
            __builtin_nontemporal_store(st, (f32x4*)(arow + jf));
        }
    };

    auto phaseB = [&](int chunk, int buf) {
        const int cj0 = chunk * 256;
        #pragma unroll 4
        for (int ks = 0; ks < 8; ++ks) {
            f16x8 pfrag[2];
            #pragma unroll
            for (int ig = 0; ig < 2; ++ig) {
                const int iloc = ig * 16 + iofs;
                const int byte = iloc * 512 + ((ks * 64 + h * 16) ^ ((iloc & 7) << 4));
                pfrag[ig] = *(const f16x8*)(P[buf] + byte);
            }
            const int jg = cj0 + ks * 32 + h * 8;
            #pragma unroll
            for (int ct = 0; ct < 2; ++ct) {
                f16x8 vfrag = *(const f16x8*)(v_b + (size_t)(c0w + ct*16 + iofs) * NTOK + jg);
                #pragma unroll
                for (int ig = 0; ig < 2; ++ig)
                    acc[ig][ct] = __builtin_amdgcn_mfma_f32_16x16x32_f16(vfrag, pfrag[ig], acc[ig][ct], 0, 0, 0);
            }
        }
    };

    phaseA(0, 0);
    LDS_BARRIER();
    for (int c = 0; c < 16; ++c) {
        if (c < 15) phaseA(c + 1, (c + 1) & 1);   // loads (kfrag) early
        phaseB(c, c & 1);                          // loads (vfrag) + PV MFMA
        __builtin_amdgcn_sched_barrier(0);         // pin: stores stay after all loads
        phaseW(c, c & 1);                          // stores issued LAST
        LDS_BARRIER();
    }

    const float g2 = gamma[0];
    #pragma unroll
    for (int ig = 0; ig < 2; ++ig) {
        #pragma unroll
        for (int ct = 0; ct < 2; ++ct) {
            #pragma unroll
            for (int r = 0; r < 4; ++r) {
                const int c = c0w + ct*16 + 4*h + r;
                const size_t bse = ((size_t)(b * NCH + c)) * NTOK + i0 + ig*16 + iofs;
                out[bse] = g2 * acc[ig][ct][r] + x[bse];
            }
        }
    }
}

extern "C" void kernel_launch(void* const* d_in, const int* in_sizes, int n_in,
                              void* d_out, int out_size, void* d_ws, size_t ws_size,
                              hipStream_t stream) {
    const float* x     = (const float*)d_in[0];
    const float* Wq    = (const float*)d_in[1];
    const float* bq    = (const float*)d_in[2];
    const float* Wk    = (const float*)d_in[3];
    const float* bk    = (const float*)d_in[4];
    const float* Wv    = (const float*)d_in[5];
    const float* bv    = (const float*)d_in[6];
    const float* gamma = (const float*)d_in[7];

    float* out = (float*)d_out;
    float* atn = out + (size_t)NB * NCH * NTOK;

    _Float16* qkT  = (_Float16*)d_ws;                          // 2 MB
    _Float16* vbuf = qkT + (size_t)NB * NTOK * 64;             // 8 MB
    float* rs_sum  = (float*)(vbuf + (size_t)NB * NCH * NTOK); // 64 KB
    _Float16* W16  = (_Float16*)(rs_sum + NB * NTOK);          // 160 KB

    hipMemsetAsync(rs_sum, 0, (size_t)NB * NTOK * sizeof(float), stream);
    wpack_kernel<<<80, 256, 0, stream>>>(Wq, Wk, Wv, W16);
    qkv_mfma_kernel<<<512, 256, 0, stream>>>(x, W16, bq, bk, bv, qkT, vbuf);
    rowsum_kernel<<<2048, 256, 0, stream>>>(qkT, rs_sum);
    attn_pv_kernel<<<512, 512, 0, stream>>>(qkT, vbuf, rs_sum, x, gamma, out, atn);
}

// Round 16
// 151.975 us; speedup vs baseline: 1.3222x; 1.3222x over previous
//
#include <hip/hip_runtime.h>

#define NB 4
#define NCH 256
#define NTOK 4096

typedef _Float16 f16x4 __attribute__((ext_vector_type(4)));
typedef _Float16 f16x8 __attribute__((ext_vector_type(8)));
typedef __fp16 h16x2 __attribute__((ext_vector_type(2)));
typedef float f32x4 __attribute__((ext_vector_type(4)));

union F2H  { h16x2 h; int i; };
union U64  { uint2 u; f16x4 h; int2 i2; };

// LDS-only barrier: do NOT drain vmcnt (stores stay in flight).
#define LDS_BARRIER() asm volatile("s_waitcnt lgkmcnt(0)\n\ts_barrier" ::: "memory")

// ---------------- K0: pack Wq/Wk/Wv -> fp16 [320][256] ----------------
__global__ __launch_bounds__(256) void wpack_kernel(
    const float* __restrict__ Wq, const float* __restrict__ Wk,
    const float* __restrict__ Wv, _Float16* __restrict__ W16)
{
    int g = blockIdx.x * 256 + threadIdx.x;
    if (g >= 320 * 64) return;
    int o = g >> 6, c4 = g & 63;
    const float* src = (o < 32) ? (Wq + o * NCH) :
                       (o < 64) ? (Wk + (o - 32) * NCH) : (Wv + (o - 64) * NCH);
    float4 v = ((const float4*)src)[c4];
    f16x4 p;
    p[0] = (_Float16)v.x; p[1] = (_Float16)v.y;
    p[2] = (_Float16)v.z; p[3] = (_Float16)v.w;
    *(f16x4*)(W16 + (size_t)o * NCH + c4 * 4) = p;
}

// ---------------- K1: QKV projection via MFMA ----------------
__global__ __launch_bounds__(256) void qkv_mfma_kernel(
    const float* __restrict__ x, const _Float16* __restrict__ W16,
    const float* __restrict__ bq, const float* __restrict__ bk,
    const float* __restrict__ bv,
    _Float16* __restrict__ qkT, _Float16* __restrict__ vbuf)
{
    __shared__ char xs[32 * 512];            // [n][c] f16, row 512B, swizzled
    __shared__ _Float16 vls[256 * 36];       // [o][n] f16, pitch 36 (72B)
    const int tid = threadIdx.x;
    const int b = blockIdx.x & 3;
    const int n0 = (blockIdx.x >> 2) << 5;
    const float* xb = x + (size_t)b * NCH * NTOK + n0;

    {   // stage: thread handles 4 consecutive c x 8 n; pack 4 c -> b64 per n
        const int c4 = tid & 63, no = tid >> 6;
        float vals[4][8];
        #pragma unroll
        for (int u = 0; u < 4; ++u) {
            const float* xr = xb + (size_t)(c4 * 4 + u) * NTOK + no * 8;
            float4 a = *(const float4*)xr;
            float4 b2 = *(const float4*)(xr + 4);
            vals[u][0]=a.x; vals[u][1]=a.y; vals[u][2]=a.z; vals[u][3]=a.w;
            vals[u][4]=b2.x; vals[u][5]=b2.y; vals[u][6]=b2.z; vals[u][7]=b2.w;
        }
        #pragma unroll
        for (int j = 0; j < 8; ++j) {
            const int n = no * 8 + j;
            f16x4 pk;
            pk[0]=(_Float16)vals[0][j]; pk[1]=(_Float16)vals[1][j];
            pk[2]=(_Float16)vals[2][j]; pk[3]=(_Float16)vals[3][j];
            *(f16x4*)(xs + n * 512 + ((c4 * 8) ^ ((n & 7) << 4))) = pk;
        }
    }
    __syncthreads();

    const int w = tid >> 6, l = tid & 63;
    const int iofs = l & 15, h = l >> 4;

    f32x4 acc[5][2];
    #pragma unroll
    for (int ot = 0; ot < 5; ++ot)
        #pragma unroll
        for (int nt = 0; nt < 2; ++nt) acc[ot][nt] = (f32x4){0.f,0.f,0.f,0.f};

    #pragma unroll
    for (int kk = 0; kk < 8; ++kk) {
        f16x8 bf[2];
        #pragma unroll
        for (int nt = 0; nt < 2; ++nt) {
            const int n = nt * 16 + iofs;
            bf[nt] = *(const f16x8*)(xs + n * 512 + ((kk * 64 + h * 16) ^ ((n & 7) << 4)));
        }
        #pragma unroll
        for (int ot = 0; ot < 5; ++ot) {
            const int og = w * 5 + ot;
            f16x8 af = *(const f16x8*)(W16 + (size_t)(og * 16 + iofs) * NCH + kk * 32 + h * 8);
            #pragma unroll
            for (int nt = 0; nt < 2; ++nt)
                acc[ot][nt] = __builtin_amdgcn_mfma_f32_16x16x32_f16(af, bf[nt], acc[ot][nt], 0, 0, 0);
        }
    }

    // epilogue: q/k direct; v -> LDS transpose tile
    #pragma unroll
    for (int ot = 0; ot < 5; ++ot) {
        const int og = w * 5 + ot;
        float4 bias;
        if (og < 2)      bias = *(const float4*)(bq + og * 16 + 4 * h);
        else if (og < 4) bias = *(const float4*)(bk + (og - 2) * 16 + 4 * h);
        else             bias = *(const float4*)(bv + (og - 4) * 16 + 4 * h);
        #pragma unroll
        for (int nt = 0; nt < 2; ++nt) {
            const int n = n0 + nt * 16 + iofs;
            f32x4 a = acc[ot][nt];
            if (og < 4) {
                f16x4 pk;
                pk[0] = (_Float16)(a[0] + bias.x); pk[1] = (_Float16)(a[1] + bias.y);
                pk[2] = (_Float16)(a[2] + bias.z); pk[3] = (_Float16)(a[3] + bias.w);
                const int col = (og < 2) ? (og * 16 + 4 * h) : (32 + (og - 2) * 16 + 4 * h);
                *(f16x4*)(qkT + (size_t)(b * NTOK + n) * 64 + col) = pk;
            } else {
                const int vr0 = (og - 4) * 16 + 4 * h;
                const int nl = nt * 16 + iofs;
                const float bb[4] = {bias.x, bias.y, bias.z, bias.w};
                #pragma unroll
                for (int r = 0; r < 4; ++r)
                    vls[(vr0 + r) * 36 + nl] = (_Float16)(a[r] + bb[r]);
            }
        }
    }
    __syncthreads();
    {   // v write-out: 4 lanes per o-row, 16B each -> 64B contiguous per row
        const int vr = tid >> 2;
        const int piece = tid & 3;
        #pragma unroll
        for (int pass = 0; pass < 4; ++pass) {
            const int row = pass * 64 + vr;
            f16x8 val = *(const f16x8*)(&vls[row * 36 + piece * 8]);
            *(f16x8*)(vbuf + (size_t)(b * NCH + row) * NTOK + n0 + piece * 8) = val;
        }
    }
}

// ---------------- K2: softmax row-sums (atomic partial sums) ----------------
__global__ __launch_bounds__(256) void rowsum_kernel(
    const _Float16* __restrict__ qkT, float* __restrict__ rs_sum)
{
    const int bid = blockIdx.x;
    const int b = bid >> 9;
    const int rem = bid & 511;
    const int ib = rem >> 3, js = rem & 7;
    const int tid = threadIdx.x;
    const int w = tid >> 6, l = tid & 63;
    const int iofs = l & 15, h = l >> 4;
    const int i16 = ib * 64 + w * 16;
    const int j0 = js * 512;
    const _Float16* qk_b = qkT + (size_t)b * NTOK * 64;

    f16x8 qfrag = *(const f16x8*)(qk_b + (size_t)(i16 + iofs) * 64 + h * 8);
    float sums[4] = {0.f, 0.f, 0.f, 0.f};
    const f32x4 zero = {0.f, 0.f, 0.f, 0.f};
    #pragma unroll 4
    for (int jt = 0; jt < 32; ++jt) {
        f16x8 kfrag = *(const f16x8*)(qk_b + (size_t)(j0 + jt*16 + iofs) * 64 + 32 + h * 8);
        f32x4 s = __builtin_amdgcn_mfma_f32_16x16x32_f16(kfrag, qfrag, zero, 0, 0, 0);
        #pragma unroll
        for (int r = 0; r < 4; ++r) sums[r] += __expf(s[r]);
    }
    float tot = sums[0] + sums[1] + sums[2] + sums[3];
    tot += __shfl_xor(tot, 16, 64);
    tot += __shfl_xor(tot, 32, 64);
    if (l < 16) atomicAdd(&rs_sum[b * NTOK + i16 + iofs], tot);
}

// ---------------- K3: fused, 64-ROW blocks (halved v/k re-read traffic) ----------------
// Grid 256 = (4b x 64 i-tiles of 64 rows), 1024 thr (16 waves), chunk = 256 j.
// phaseA: wave w does 16 j x 4 i-groups QK^T -> exp -> P(f16) -> LDS.
// phaseB: PV GEMM, wave owns 16 c, 4 i-groups. phaseW: full-line nt stores.
// LDS P dbuf 2x[64][256] f16 = 64KB. Barriers LDS-only.
__global__ __launch_bounds__(1024, 1) void attn_pv_kernel(
    const _Float16* __restrict__ qkT, const _Float16* __restrict__ vbuf,
    const float* __restrict__ rs_sum, const float* __restrict__ x,
    const float* __restrict__ gamma, float* __restrict__ out, float* __restrict__ atn)
{
    __shared__ char P[2][64 * 512];
    const int tid = threadIdx.x;
    const int w = tid >> 6, l = tid & 63;   // w: 0..15
    const int iofs = l & 15, h = l >> 4;
    const int xk = blockIdx.x & 7, rest = blockIdx.x >> 3;   // grid 256
    const int b = xk >> 1;
    const int itb = (rest << 1) | (xk & 1);   // 0..63
    const int i0 = itb << 6;                  // 64 i-rows per block

    const _Float16* qk_b = qkT + (size_t)b * NTOK * 64;
    const _Float16* v_b  = vbuf + (size_t)b * NCH * NTOK;
    float* atn_b = atn + (size_t)b * NTOK * NTOK;
    const int c0w = w * 16;                   // wave owns 16 c
    const float LOG2E = 1.44269504f;

    f16x8 qfrag[4];
    float rsl[4];
    #pragma unroll
    for (int ig = 0; ig < 4; ++ig) {
        qfrag[ig] = *(const f16x8*)(qk_b + (size_t)(i0 + ig*16 + iofs) * 64 + h * 8);
        rsl[ig] = -__log2f(rs_sum[b * NTOK + i0 + ig*16 + iofs]);
    }

    const f32x4 zero = {0.f, 0.f, 0.f, 0.f};
    f32x4 acc[4];
    #pragma unroll
    for (int ig = 0; ig < 4; ++ig) acc[ig] = zero;

    // phase A: wave w computes S^T for j in [chunk*256 + w*16, +16), 4 i-groups
    auto phaseA = [&](int chunk, int buf) {
        const int jg = chunk * 256 + w * 16;
        f16x8 kfrag = *(const f16x8*)(qk_b + (size_t)(jg + iofs) * 64 + 32 + h * 8);
        #pragma unroll
        for (int ig = 0; ig < 4; ++ig) {
            f32x4 s = __builtin_amdgcn_mfma_f32_16x16x32_f16(kfrag, qfrag[ig], zero, 0, 0, 0);
            f32x4 pv;
            #pragma unroll
            for (int r = 0; r < 4; ++r)
                pv[r] = __builtin_amdgcn_exp2f(__builtin_fmaf(s[r], LOG2E, rsl[ig]));
            F2H p0, p1;
            p0.h = __builtin_amdgcn_cvt_pkrtz(pv[0], pv[1]);
            p1.h = __builtin_amdgcn_cvt_pkrtz(pv[2], pv[3]);
            const int iloc = ig * 16 + iofs;
            const int jloc = w * 16 + 4 * h;
            const int byte = iloc * 512 + ((jloc * 2) ^ ((iloc & 7) << 4));
            U64 u; u.i2.x = p0.i; u.i2.y = p1.i;
            *(int2*)(P[buf] + byte) = u.i2;
        }
    };

    // phase W: LDS -> atn. 1024 thr = 64 rows x 16 lanes; 16 lanes x 16B = 256B
    // contiguous per instruction (2 full 128B lines). nt.
    auto phaseW = [&](int chunk, int buf) {
        const int lane16 = tid & 15;
        const int row = tid >> 4;           // 0..63
        const int sw = (row & 7) << 4;
        float* arow = atn_b + (size_t)(i0 + row) * NTOK + chunk * 256;
        #pragma unroll
        for (int u = 0; u < 4; ++u) {
            const int jf = u * 64 + lane16 * 4;       // f16 idx within 256
            U64 v; v.i2 = *(const int2*)(P[buf] + row * 512 + ((jf * 2) ^ sw));
            f32x4 st = {(float)v.h[0], (float)v.h[1], (float)v.h[2], (float)v.h[3]};
            __builtin_nontemporal_store(st, (f32x4*)(arow + jf));
        }
    };

    // phase B: PV GEMM over the chunk. wave owns c-range [c0w, +16), 4 i-groups
    auto phaseB = [&](int chunk, int buf) {
        const int cj0 = chunk * 256;
        #pragma unroll 4
        for (int ks = 0; ks < 8; ++ks) {
            f16x8 pfrag[4];
            #pragma unroll
            for (int ig = 0; ig < 4; ++ig) {
                const int iloc = ig * 16 + iofs;
                const int byte = iloc * 512 + ((ks * 64 + h * 16) ^ ((iloc & 7) << 4));
                pfrag[ig] = *(const f16x8*)(P[buf] + byte);
            }
            const int jg = cj0 + ks * 32 + h * 8;
            f16x8 vfrag = *(const f16x8*)(v_b + (size_t)(c0w + iofs) * NTOK + jg);
            #pragma unroll
            for (int ig = 0; ig < 4; ++ig)
                acc[ig] = __builtin_amdgcn_mfma_f32_16x16x32_f16(vfrag, pfrag[ig], acc[ig], 0, 0, 0);
        }
    };

    phaseA(0, 0);
    LDS_BARRIER();
    for (int c = 0; c < 16; ++c) {
        if (c < 15) phaseA(c + 1, (c + 1) & 1);   // loads (kfrag) early
        phaseB(c, c & 1);                          // loads (vfrag) + PV MFMA
        __builtin_amdgcn_sched_barrier(0);         // stores stay after loads
        phaseW(c, c & 1);                          // stores issued last
        LDS_BARRIER();
    }

    // epilogue: out[b][c][i] = gamma*acc + x
    const float g2 = gamma[0];
    #pragma unroll
    for (int ig = 0; ig < 4; ++ig) {
        #pragma unroll
        for (int r = 0; r < 4; ++r) {
            const int c = c0w + 4*h + r;
            const size_t bse = ((size_t)(b * NCH + c)) * NTOK + i0 + ig*16 + iofs;
            out[bse] = g2 * acc[ig][r] + x[bse];
        }
    }
}

extern "C" void kernel_launch(void* const* d_in, const int* in_sizes, int n_in,
                              void* d_out, int out_size, void* d_ws, size_t ws_size,
                              hipStream_t stream) {
    const float* x     = (const float*)d_in[0];
    const float* Wq    = (const float*)d_in[1];
    const float* bq    = (const float*)d_in[2];
    const float* Wk    = (const float*)d_in[3];
    const float* bk    = (const float*)d_in[4];
    const float* Wv    = (const float*)d_in[5];
    const float* bv    = (const float*)d_in[6];
    const float* gamma = (const float*)d_in[7];

    float* out = (float*)d_out;
    float* atn = out + (size_t)NB * NCH * NTOK;

    _Float16* qkT  = (_Float16*)d_ws;                          // 2 MB
    _Float16* vbuf = qkT + (size_t)NB * NTOK * 64;             // 8 MB
    float* rs_sum  = (float*)(vbuf + (size_t)NB * NCH * NTOK); // 64 KB
    _Float16* W16  = (_Float16*)(rs_sum + NB * NTOK);          // 160 KB

    hipMemsetAsync(rs_sum, 0, (size_t)NB * NTOK * sizeof(float), stream);
    wpack_kernel<<<80, 256, 0, stream>>>(Wq, Wk, Wv, W16);
    qkv_mfma_kernel<<<512, 256, 0, stream>>>(x, W16, bq, bk, bv, qkT, vbuf);
    rowsum_kernel<<<2048, 256, 0, stream>>>(qkT, rs_sum);
    attn_pv_kernel<<<256, 1024, 0, stream>>>(qkT, vbuf, rs_sum, x, gamma, out, atn);
}

// Round 17
// 145.196 us; speedup vs baseline: 1.3840x; 1.0467x over previous
//
#include <hip/hip_runtime.h>

#define NB 4
#define NCH 256
#define NTOK 4096

typedef _Float16 f16x4 __attribute__((ext_vector_type(4)));
typedef _Float16 f16x8 __attribute__((ext_vector_type(8)));
typedef __fp16 h16x2 __attribute__((ext_vector_type(2)));
typedef float f32x4 __attribute__((ext_vector_type(4)));

union F2H  { h16x2 h; int i; };
union U64  { uint2 u; f16x4 h; int2 i2; };

// LDS-only barrier: do NOT drain vmcnt (stores stay in flight).
#define LDS_BARRIER() asm volatile("s_waitcnt lgkmcnt(0)\n\ts_barrier" ::: "memory")

// ---------------- K0: pack Wq/Wk/Wv -> fp16 [320][256] ----------------
__global__ __launch_bounds__(256) void wpack_kernel(
    const float* __restrict__ Wq, const float* __restrict__ Wk,
    const float* __restrict__ Wv, _Float16* __restrict__ W16)
{
    int g = blockIdx.x * 256 + threadIdx.x;
    if (g >= 320 * 64) return;
    int o = g >> 6, c4 = g & 63;
    const float* src = (o < 32) ? (Wq + o * NCH) :
                       (o < 64) ? (Wk + (o - 32) * NCH) : (Wv + (o - 64) * NCH);
    float4 v = ((const float4*)src)[c4];
    f16x4 p;
    p[0] = (_Float16)v.x; p[1] = (_Float16)v.y;
    p[2] = (_Float16)v.z; p[3] = (_Float16)v.w;
    *(f16x4*)(W16 + (size_t)o * NCH + c4 * 4) = p;
}

// ---------------- K1: QKV projection via MFMA ----------------
__global__ __launch_bounds__(256) void qkv_mfma_kernel(
    const float* __restrict__ x, const _Float16* __restrict__ W16,
    const float* __restrict__ bq, const float* __restrict__ bk,
    const float* __restrict__ bv,
    _Float16* __restrict__ qkT, _Float16* __restrict__ vbuf)
{
    __shared__ char xs[32 * 512];            // [n][c] f16, row 512B, swizzled
    __shared__ _Float16 vls[256 * 36];       // [o][n] f16, pitch 36 (72B)
    const int tid = threadIdx.x;
    const int b = blockIdx.x & 3;
    const int n0 = (blockIdx.x >> 2) << 5;
    const float* xb = x + (size_t)b * NCH * NTOK + n0;

    {   // stage: thread handles 4 consecutive c x 8 n; pack 4 c -> b64 per n
        const int c4 = tid & 63, no = tid >> 6;
        float vals[4][8];
        #pragma unroll
        for (int u = 0; u < 4; ++u) {
            const float* xr = xb + (size_t)(c4 * 4 + u) * NTOK + no * 8;
            float4 a = *(const float4*)xr;
            float4 b2 = *(const float4*)(xr + 4);
            vals[u][0]=a.x; vals[u][1]=a.y; vals[u][2]=a.z; vals[u][3]=a.w;
            vals[u][4]=b2.x; vals[u][5]=b2.y; vals[u][6]=b2.z; vals[u][7]=b2.w;
        }
        #pragma unroll
        for (int j = 0; j < 8; ++j) {
            const int n = no * 8 + j;
            f16x4 pk;
            pk[0]=(_Float16)vals[0][j]; pk[1]=(_Float16)vals[1][j];
            pk[2]=(_Float16)vals[2][j]; pk[3]=(_Float16)vals[3][j];
            *(f16x4*)(xs + n * 512 + ((c4 * 8) ^ ((n & 7) << 4))) = pk;
        }
    }
    __syncthreads();

    const int w = tid >> 6, l = tid & 63;
    const int iofs = l & 15, h = l >> 4;

    f32x4 acc[5][2];
    #pragma unroll
    for (int ot = 0; ot < 5; ++ot)
        #pragma unroll
        for (int nt = 0; nt < 2; ++nt) acc[ot][nt] = (f32x4){0.f,0.f,0.f,0.f};

    #pragma unroll
    for (int kk = 0; kk < 8; ++kk) {
        f16x8 bf[2];
        #pragma unroll
        for (int nt = 0; nt < 2; ++nt) {
            const int n = nt * 16 + iofs;
            bf[nt] = *(const f16x8*)(xs + n * 512 + ((kk * 64 + h * 16) ^ ((n & 7) << 4)));
        }
        #pragma unroll
        for (int ot = 0; ot < 5; ++ot) {
            const int og = w * 5 + ot;
            f16x8 af = *(const f16x8*)(W16 + (size_t)(og * 16 + iofs) * NCH + kk * 32 + h * 8);
            #pragma unroll
            for (int nt = 0; nt < 2; ++nt)
                acc[ot][nt] = __builtin_amdgcn_mfma_f32_16x16x32_f16(af, bf[nt], acc[ot][nt], 0, 0, 0);
        }
    }

    // epilogue: q/k direct; v -> LDS transpose tile
    #pragma unroll
    for (int ot = 0; ot < 5; ++ot) {
        const int og = w * 5 + ot;
        float4 bias;
        if (og < 2)      bias = *(const float4*)(bq + og * 16 + 4 * h);
        else if (og < 4) bias = *(const float4*)(bk + (og - 2) * 16 + 4 * h);
        else             bias = *(const float4*)(bv + (og - 4) * 16 + 4 * h);
        #pragma unroll
        for (int nt = 0; nt < 2; ++nt) {
            const int n = n0 + nt * 16 + iofs;
            f32x4 a = acc[ot][nt];
            if (og < 4) {
                f16x4 pk;
                pk[0] = (_Float16)(a[0] + bias.x); pk[1] = (_Float16)(a[1] + bias.y);
                pk[2] = (_Float16)(a[2] + bias.z); pk[3] = (_Float16)(a[3] + bias.w);
                const int col = (og < 2) ? (og * 16 + 4 * h) : (32 + (og - 2) * 16 + 4 * h);
                *(f16x4*)(qkT + (size_t)(b * NTOK + n) * 64 + col) = pk;
            } else {
                const int vr0 = (og - 4) * 16 + 4 * h;
                const int nl = nt * 16 + iofs;
                const float bb[4] = {bias.x, bias.y, bias.z, bias.w};
                #pragma unroll
                for (int r = 0; r < 4; ++r)
                    vls[(vr0 + r) * 36 + nl] = (_Float16)(a[r] + bb[r]);
            }
        }
    }
    __syncthreads();
    {   // v write-out: 4 lanes per o-row, 16B each -> 64B contiguous per row
        const int vr = tid >> 2;
        const int piece = tid & 3;
        #pragma unroll
        for (int pass = 0; pass < 4; ++pass) {
            const int row = pass * 64 + vr;
            f16x8 val = *(const f16x8*)(&vls[row * 36 + piece * 8]);
            *(f16x8*)(vbuf + (size_t)(b * NCH + row) * NTOK + n0 + piece * 8) = val;
        }
    }
}

// ---------------- K2: softmax row-sums (atomic partial sums) ----------------
__global__ __launch_bounds__(256) void rowsum_kernel(
    const _Float16* __restrict__ qkT, float* __restrict__ rs_sum)
{
    const int bid = blockIdx.x;
    const int b = bid >> 9;
    const int rem = bid & 511;
    const int ib = rem >> 3, js = rem & 7;
    const int tid = threadIdx.x;
    const int w = tid >> 6, l = tid & 63;
    const int iofs = l & 15, h = l >> 4;
    const int i16 = ib * 64 + w * 16;
    const int j0 = js * 512;
    const _Float16* qk_b = qkT + (size_t)b * NTOK * 64;

    f16x8 qfrag = *(const f16x8*)(qk_b + (size_t)(i16 + iofs) * 64 + h * 8);
    float sums[4] = {0.f, 0.f, 0.f, 0.f};
    const f32x4 zero = {0.f, 0.f, 0.f, 0.f};
    #pragma unroll 4
    for (int jt = 0; jt < 32; ++jt) {
        f16x8 kfrag = *(const f16x8*)(qk_b + (size_t)(j0 + jt*16 + iofs) * 64 + 32 + h * 8);
        f32x4 s = __builtin_amdgcn_mfma_f32_16x16x32_f16(kfrag, qfrag, zero, 0, 0, 0);
        #pragma unroll
        for (int r = 0; r < 4; ++r) sums[r] += __expf(s[r]);
    }
    float tot = sums[0] + sums[1] + sums[2] + sums[3];
    tot += __shfl_xor(tot, 16, 64);
    tot += __shfl_xor(tot, 32, 64);
    if (l < 16) atomicAdd(&rs_sum[b * NTOK + i16 + iofs], tot);
}

// ---------------- K3: fused, 128-ROW x 128-C blocks (v-traffic halved again) ----------------
// Grid 256 = (4b x 32 it x 2 ch), 1024 thr (16 waves), chunk = 256 j.
// phaseA: wave w owns 16 j x all 8 i-groups: QK^T -> exp -> P(f16) -> LDS.
// phaseB: wave (s = w>>1, khalf = w&1): c-slice s (16 c), k-half (4 ks), all 8 ig.
//         Partial accs summed cross-wave-pair via LDS in epilogue.
// phaseW: owner (ch == chunk&1) streams 128 rows x 256 j, full-128B-line nt stores.
// LDS: P dbuf 2x[128][256] f16 = 128 KB.
__global__ __launch_bounds__(1024, 1) void attn_pv_kernel(
    const _Float16* __restrict__ qkT, const _Float16* __restrict__ vbuf,
    const float* __restrict__ rs_sum, const float* __restrict__ x,
    const float* __restrict__ gamma, float* __restrict__ out, float* __restrict__ atn)
{
    __shared__ char P[2][128 * 512];
    const int tid = threadIdx.x;
    const int w = tid >> 6, l = tid & 63;   // w: 0..15
    const int iofs = l & 15, h = l >> 4;
    const int id = blockIdx.x;              // grid 256
    const int xk = id & 7;
    const int b  = xk >> 1;
    const int rest = id >> 3;               // 0..31
    const int ch = rest & 1;
    const int itb = ((rest >> 1) << 1) | (xk & 1);   // 0..31
    const int i0 = itb << 7;                // 128 i-rows per block

    const _Float16* qk_b = qkT + (size_t)b * NTOK * 64;
    const _Float16* v_b  = vbuf + (size_t)b * NCH * NTOK;
    float* atn_b = atn + (size_t)b * NTOK * NTOK;
    const int s = w >> 1;                   // c-slice 0..7
    const int khalf = w & 1;
    const int c0w = ch * 128 + s * 16;      // 16-c slice
    const float LOG2E = 1.44269504f;

    f16x8 qfrag[8];
    float rsl[8];
    #pragma unroll
    for (int ig = 0; ig < 8; ++ig) {
        qfrag[ig] = *(const f16x8*)(qk_b + (size_t)(i0 + ig*16 + iofs) * 64 + h * 8);
        rsl[ig] = -__log2f(rs_sum[b * NTOK + i0 + ig*16 + iofs]);
    }

    const f32x4 zero = {0.f, 0.f, 0.f, 0.f};
    f32x4 acc[8];
    #pragma unroll
    for (int ig = 0; ig < 8; ++ig) acc[ig] = zero;

    // phase A: wave w computes S^T for j in [chunk*256 + w*16, +16), 8 i-groups
    auto phaseA = [&](int chunk, int buf) {
        const int jg = chunk * 256 + w * 16;
        f16x8 kfrag = *(const f16x8*)(qk_b + (size_t)(jg + iofs) * 64 + 32 + h * 8);
        #pragma unroll
        for (int ig = 0; ig < 8; ++ig) {
            f32x4 sv = __builtin_amdgcn_mfma_f32_16x16x32_f16(kfrag, qfrag[ig], zero, 0, 0, 0);
            f32x4 pv;
            #pragma unroll
            for (int r = 0; r < 4; ++r)
                pv[r] = __builtin_amdgcn_exp2f(__builtin_fmaf(sv[r], LOG2E, rsl[ig]));
            F2H p0, p1;
            p0.h = __builtin_amdgcn_cvt_pkrtz(pv[0], pv[1]);
            p1.h = __builtin_amdgcn_cvt_pkrtz(pv[2], pv[3]);
            const int iloc = ig * 16 + iofs;
            const int jloc = w * 16 + 4 * h;
            const int byte = iloc * 512 + ((jloc * 2) ^ ((iloc & 7) << 4));
            U64 u; u.i2.x = p0.i; u.i2.y = p1.i;
            *(int2*)(P[buf] + byte) = u.i2;
        }
    };

    // phase W (owner only): LDS -> atn. 1024 thr = 128 rows x 8 lanes;
    // 8 lanes x 16B = one full 128B line per store instr. nt. 8 stores/thread.
    auto phaseW = [&](int chunk, int buf) {
        const int lg = tid & 7;
        const int row = tid >> 3;           // 0..127
        const int sw = (row & 7) << 4;
        float* arow = atn_b + (size_t)(i0 + row) * NTOK + chunk * 256;
        const char* prow = P[buf] + row * 512;
        #pragma unroll
        for (int u = 0; u < 8; ++u) {
            const int jf = u * 32 + lg * 4;           // f16 idx 0..255
            U64 v; v.i2 = *(const int2*)(prow + ((jf * 2) ^ sw));
            f32x4 st = {(float)v.h[0], (float)v.h[1], (float)v.h[2], (float)v.h[3]};
            __builtin_nontemporal_store(st, (f32x4*)(arow + jf));
        }
    };

    // phase B: PV GEMM. wave (s, khalf): 16 c, ks in [khalf*4, +4), all 8 ig.
    auto phaseB = [&](int chunk, int buf) {
        const int cj0 = chunk * 256;
        #pragma unroll
        for (int kk = 0; kk < 4; ++kk) {
            const int ks = khalf * 4 + kk;
            const int jg = cj0 + ks * 32 + h * 8;
            f16x8 vfrag = *(const f16x8*)(v_b + (size_t)(c0w + iofs) * NTOK + jg);
            #pragma unroll
            for (int ig = 0; ig < 8; ++ig) {
                const int iloc = ig * 16 + iofs;
                const int byte = iloc * 512 + ((ks * 64 + h * 16) ^ ((iloc & 7) << 4));
                f16x8 pfrag = *(const f16x8*)(P[buf] + byte);
                acc[ig] = __builtin_amdgcn_mfma_f32_16x16x32_f16(vfrag, pfrag, acc[ig], 0, 0, 0);
            }
        }
    };

    phaseA(0, 0);
    LDS_BARRIER();
    for (int c = 0; c < 16; ++c) {
        if (c < 15) phaseA(c + 1, (c + 1) & 1);   // loads (kfrag) early
        phaseB(c, c & 1);                          // loads (vfrag) + PV MFMA
        __builtin_amdgcn_sched_barrier(0);         // stores stay after loads
        if (ch == (c & 1)) phaseW(c, c & 1);       // stores issued last (owner)
        LDS_BARRIER();
    }

    // epilogue: cross-wave-pair acc reduction via LDS, then out = gamma*acc + x.
    // Odd waves (khalf=1) dump acc; even waves add partner's and store.
    {
        float* red = (float*)P[0];   // reuse P buffer (64 KB used)
        if (khalf) {
            // layout [s][r 0..31][lane]: addr floats = s*2048 + rr*64 + l
            #pragma unroll
            for (int ig = 0; ig < 8; ++ig)
                #pragma unroll
                for (int r = 0; r < 4; ++r)
                    red[s * 2048 + (ig * 4 + r) * 64 + l] = acc[ig][r];
        }
        LDS_BARRIER();
        if (!khalf) {
            const float g2 = gamma[0];
            #pragma unroll
            for (int ig = 0; ig < 8; ++ig) {
                #pragma unroll
                for (int r = 0; r < 4; ++r) {
                    float a2 = acc[ig][r] + red[s * 2048 + (ig * 4 + r) * 64 + l];
                    const int c = c0w + 4*h + r;
                    const size_t bse = ((size_t)(b * NCH + c)) * NTOK + i0 + ig*16 + iofs;
                    out[bse] = g2 * a2 + x[bse];
                }
            }
        }
    }
}

extern "C" void kernel_launch(void* const* d_in, const int* in_sizes, int n_in,
                              void* d_out, int out_size, void* d_ws, size_t ws_size,
                              hipStream_t stream) {
    const float* x     = (const float*)d_in[0];
    const float* Wq    = (const float*)d_in[1];
    const float* bq    = (const float*)d_in[2];
    const float* Wk    = (const float*)d_in[3];
    const float* bk    = (const float*)d_in[4];
    const float* Wv    = (const float*)d_in[5];
    const float* bv    = (const float*)d_in[6];
    const float* gamma = (const float*)d_in[7];

    float* out = (float*)d_out;
    float* atn = out + (size_t)NB * NCH * NTOK;

    _Float16* qkT  = (_Float16*)d_ws;                          // 2 MB
    _Float16* vbuf = qkT + (size_t)NB * NTOK * 64;             // 8 MB
    float* rs_sum  = (float*)(vbuf + (size_t)NB * NCH * NTOK); // 64 KB
    _Float16* W16  = (_Float16*)(rs_sum + NB * NTOK);          // 160 KB

    hipMemsetAsync(rs_sum, 0, (size_t)NB * NTOK * sizeof(float), stream);
    wpack_kernel<<<80, 256, 0, stream>>>(Wq, Wk, Wv, W16);
    qkv_mfma_kernel<<<512, 256, 0, stream>>>(x, W16, bq, bk, bv, qkT, vbuf);
    rowsum_kernel<<<2048, 256, 0, stream>>>(qkT, rs_sum);
    attn_pv_kernel<<<256, 1024, 0, stream>>>(qkT, vbuf, rs_sum, x, gamma, out, atn);
}